// Round 3
// baseline (1769.944 us; speedup 1.0000x reference)
//
#include <hip/hip_runtime.h>

#define BB 64
#define SS 2048
#define II 128
#define HH 256
#define OO 128

// ---------------------------------------------------------------------------
// Prep: transpose W_ih -> [I][H], W_fc -> [H][O], combine biases.
// ---------------------------------------------------------------------------
__global__ void prep_kernel(const float* __restrict__ W_ih, const float* __restrict__ b_ih,
                            const float* __restrict__ b_hh, const float* __restrict__ W_fc,
                            float* __restrict__ wihT, float* __restrict__ wfcT,
                            float* __restrict__ biasc) {
    int idx = blockIdx.x * 256 + threadIdx.x;
    if (idx < HH * II) {            // W_ih [H][I] -> wihT [I][H]
        int j = idx / II, k = idx % II;
        wihT[k * HH + j] = W_ih[idx];
    }
    if (idx < OO * HH) {            // W_fc [O][H] -> wfcT [H][O]
        int j = idx / HH, k = idx % HH;
        wfcT[k * OO + j] = W_fc[idx];
    }
    if (idx < HH) biasc[idx] = b_ih[idx] + b_hh[idx];
}

// ---------------------------------------------------------------------------
// Generic row-major GEMM: C[r][j] = sum_k A[r][k] * Wt[k][j] + bias[j]
// 256 threads, 8x8 micro-tile per thread.
// ---------------------------------------------------------------------------
template<int KD, int JD, int RT>
__global__ __launch_bounds__(256, 2)
void gemm_rk(const float* __restrict__ A, const float* __restrict__ Wt,
             const float* __restrict__ bias, float* __restrict__ C) {
    constexpr int KT = 64;
    constexpr int TJ = JD / 8;      // threads along j
    constexpr int TR = RT / 8;      // threads along r  (TJ*TR == 256)
    static_assert(TJ * TR == 256, "bad tiling");

    __shared__ __align__(16) float a_lds[RT][KT];
    __shared__ __align__(16) float w_lds[KT][JD];

    const int tid = threadIdx.x;
    const int tj = tid % TJ;
    const int tr = tid / TJ;
    const long r0 = (long)blockIdx.x * RT;

    float acc[8][8];
#pragma unroll
    for (int r = 0; r < 8; ++r)
#pragma unroll
        for (int j = 0; j < 8; ++j) acc[r][j] = 0.0f;

    for (int kt = 0; kt < KD; kt += KT) {
        {
            constexpr int NF4 = RT * KT / 4;
#pragma unroll
            for (int f = 0; f < NF4 / 256; ++f) {
                int fl = f * 256 + tid;
                int rr = fl / (KT / 4), kk4 = fl % (KT / 4);
                *(float4*)&a_lds[rr][kk4 * 4] =
                    *(const float4*)&A[(r0 + rr) * KD + kt + kk4 * 4];
            }
        }
        {
            constexpr int NF4 = KT * JD / 4;
#pragma unroll
            for (int f = 0; f < NF4 / 256; ++f) {
                int fl = f * 256 + tid;
                int kk = fl / (JD / 4), jj4 = fl % (JD / 4);
                *(float4*)&w_lds[kk][jj4 * 4] =
                    *(const float4*)&Wt[(long)(kt + kk) * JD + jj4 * 4];
            }
        }
        __syncthreads();

#pragma unroll 4
        for (int k4 = 0; k4 < KT; k4 += 4) {
            float4 xv[8];
#pragma unroll
            for (int r = 0; r < 8; ++r)
                xv[r] = *(const float4*)&a_lds[tr * 8 + r][k4];
#pragma unroll
            for (int i = 0; i < 4; ++i) {
                float4 wa = *(const float4*)&w_lds[k4 + i][tj * 8];
                float4 wb = *(const float4*)&w_lds[k4 + i][tj * 8 + 4];
#pragma unroll
                for (int r = 0; r < 8; ++r) {
                    float xs = (i == 0) ? xv[r].x : (i == 1) ? xv[r].y
                             : (i == 2) ? xv[r].z : xv[r].w;
                    acc[r][0] = fmaf(xs, wa.x, acc[r][0]);
                    acc[r][1] = fmaf(xs, wa.y, acc[r][1]);
                    acc[r][2] = fmaf(xs, wa.z, acc[r][2]);
                    acc[r][3] = fmaf(xs, wa.w, acc[r][3]);
                    acc[r][4] = fmaf(xs, wb.x, acc[r][4]);
                    acc[r][5] = fmaf(xs, wb.y, acc[r][5]);
                    acc[r][6] = fmaf(xs, wb.z, acc[r][6]);
                    acc[r][7] = fmaf(xs, wb.w, acc[r][7]);
                }
            }
        }
        __syncthreads();
    }

    float4 b0 = *(const float4*)&bias[tj * 8];
    float4 b1 = *(const float4*)&bias[tj * 8 + 4];
#pragma unroll
    for (int r = 0; r < 8; ++r) {
        long row = r0 + tr * 8 + r;
        float4 o0, o1;
        o0.x = acc[r][0] + b0.x; o0.y = acc[r][1] + b0.y;
        o0.z = acc[r][2] + b0.z; o0.w = acc[r][3] + b0.w;
        o1.x = acc[r][4] + b1.x; o1.y = acc[r][5] + b1.y;
        o1.z = acc[r][6] + b1.z; o1.w = acc[r][7] + b1.w;
        *(float4*)&C[row * JD + tj * 8]     = o0;
        *(float4*)&C[row * JD + tj * 8 + 4] = o1;
    }
}

// ---------------------------------------------------------------------------
// Sequential scan v2: h_t = tanh(xp_t + h_{t-1} @ W_hh^T), in-place.
// 64 blocks (one per batch) x 512 threads (8 waves).
// Wave w owns outputs [w*32, w*32+32). Lane l: sl = l&15 -> outputs
// j0 = w*32+sl*2, j0+1; q = l>>4 -> k-slice [q*64, q*64+64).
// Per thread: 128 FMAs (4 ILP chains), then in-wave butterfly reduce
// (shfl_xor 16, 32). h double-buffered in LDS, bank-staggered quarters
// (68-float stride -> 4 distinct ds_read addrs per instr on disjoint banks).
// ONE barrier per step.
// ---------------------------------------------------------------------------
__global__ __launch_bounds__(512, 2)
void rnn_scan(const float* __restrict__ W_hh, float* __restrict__ hid) {
    const int b   = blockIdx.x;
    const int tid = threadIdx.x;
    const int w   = tid >> 6;
    const int l   = tid & 63;
    const int sl  = l & 15;
    const int q   = l >> 4;

    const int j0 = w * 32 + sl * 2;      // two outputs j0, j0+1
    const int k0 = q * 64;               // k range [k0, k0+64)

    // quarter q of h lives at offset q*68 floats: q*272B -> bank q*4 stagger
    __shared__ __align__(16) float h_lds[2][4 * 68];

    // per-thread weights: rows j0, j0+1, cols [k0, k0+64)
    float4 wA[16], wB[16];
#pragma unroll
    for (int i = 0; i < 16; ++i) {
        wA[i] = *(const float4*)&W_hh[(size_t)j0 * HH + k0 + i * 4];
        wB[i] = *(const float4*)&W_hh[(size_t)(j0 + 1) * HH + k0 + i * 4];
    }

    for (int i = tid; i < 2 * 4 * 68; i += 512) ((float*)h_lds)[i] = 0.0f;

    float* __restrict__ base = hid + (size_t)b * SS * HH;
    float2 xp0 = make_float2(0.f, 0.f), xp1 = xp0;
    if (q == 0) {
        xp0 = *(const float2*)&base[j0];
        xp1 = *(const float2*)&base[HH + j0];
    }
    __syncthreads();

#pragma unroll 1
    for (int t = 0; t < SS; ++t) {
        // prefetch xproj for t+2 (read precedes the overwrite at t)
        float2 xp2 = make_float2(0.f, 0.f);
        if (q == 0 && t + 2 < SS)
            xp2 = *(const float2*)&base[(size_t)(t + 2) * HH + j0];

        const float4* hb = (const float4*)&h_lds[t & 1][q * 68];
        float a0 = 0.f, a1 = 0.f, c0 = 0.f, c1 = 0.f;
#pragma unroll
        for (int i = 0; i < 16; i += 2) {
            float4 h0 = hb[i];
            float4 h1 = hb[i + 1];
            a0 = fmaf(h0.x, wA[i].x, a0);
            a0 = fmaf(h0.y, wA[i].y, a0);
            a0 = fmaf(h0.z, wA[i].z, a0);
            a0 = fmaf(h0.w, wA[i].w, a0);
            a1 = fmaf(h1.x, wA[i + 1].x, a1);
            a1 = fmaf(h1.y, wA[i + 1].y, a1);
            a1 = fmaf(h1.z, wA[i + 1].z, a1);
            a1 = fmaf(h1.w, wA[i + 1].w, a1);
            c0 = fmaf(h0.x, wB[i].x, c0);
            c0 = fmaf(h0.y, wB[i].y, c0);
            c0 = fmaf(h0.z, wB[i].z, c0);
            c0 = fmaf(h0.w, wB[i].w, c0);
            c1 = fmaf(h1.x, wB[i + 1].x, c1);
            c1 = fmaf(h1.y, wB[i + 1].y, c1);
            c1 = fmaf(h1.z, wB[i + 1].z, c1);
            c1 = fmaf(h1.w, wB[i + 1].w, c1);
        }
        float sA = a0 + a1;
        float sB = c0 + c1;
        // butterfly over the 4 k-quarters (lanes sl, sl+16, sl+32, sl+48)
        sA += __shfl_xor(sA, 16, 64);
        sA += __shfl_xor(sA, 32, 64);
        sB += __shfl_xor(sB, 16, 64);
        sB += __shfl_xor(sB, 32, 64);

        if (q == 0) {
            float s0 = xp0.x + sA;
            float s1 = xp0.y + sB;
            s0 = fminf(fmaxf(s0, -15.0f), 15.0f);
            s1 = fminf(fmaxf(s1, -15.0f), 15.0f);
            float e0 = __expf(2.0f * s0);
            float e1 = __expf(2.0f * s1);
            float hn0 = (e0 - 1.0f) / (e0 + 1.0f);
            float hn1 = (e1 - 1.0f) / (e1 + 1.0f);
            int qq = j0 >> 6, ii = j0 & 63;
            *(float2*)&h_lds[(t & 1) ^ 1][qq * 68 + ii] = make_float2(hn0, hn1);
            *(float2*)&base[(size_t)t * HH + j0] = make_float2(hn0, hn1);
        }
        __syncthreads();
        xp0 = xp1;
        xp1 = xp2;
    }
}

// ---------------------------------------------------------------------------
extern "C" void kernel_launch(void* const* d_in, const int* in_sizes, int n_in,
                              void* d_out, int out_size, void* d_ws, size_t ws_size,
                              hipStream_t stream) {
    const float* x    = (const float*)d_in[0];
    const float* W_ih = (const float*)d_in[1];
    const float* W_hh = (const float*)d_in[2];
    const float* b_ih = (const float*)d_in[3];
    const float* b_hh = (const float*)d_in[4];
    const float* W_fc = (const float*)d_in[5];
    const float* b_fc = (const float*)d_in[6];

    float* out_fc  = (float*)d_out;                          // [B][S][O]
    float* hidden  = (float*)d_out + (size_t)BB * SS * OO;   // [B][S][H]

    float* wihT  = (float*)d_ws;                 // [I][H]
    float* wfcT  = wihT + II * HH;               // [H][O]
    float* biasc = wfcT + HH * OO;               // [H]

    const long NR = (long)BB * SS;               // 131072 rows

    prep_kernel<<<128, 256, 0, stream>>>(W_ih, b_ih, b_hh, W_fc, wihT, wfcT, biasc);
    gemm_rk<II, HH, 64><<<NR / 64, 256, 0, stream>>>(x, wihT, biasc, hidden);
    rnn_scan<<<BB, 512, 0, stream>>>(W_hh, hidden);
    gemm_rk<HH, OO, 128><<<NR / 128, 256, 0, stream>>>(hidden, wfcT, b_fc, out_fc);
}